// Round 6
// baseline (244.985 us; speedup 1.0000x reference)
//
#include <hip/hip_runtime.h>

// ModulatedConv2d: B=16, IN=512, OUT=512, STYLE=512, K=3, H=W=32
// out[b,o] = scale[b,o] * conv2d(x[b,i]*s[b,i], W[o,i])   (shared weights!)
// Conv = one implicit GEMM: M=512 out-ch, N=16384 (b,px), K=9x512.
// x staged as zero-padded NHWC bf16 -> no boundary masking.
//
// R8:  reg-staged A+B LDS pipeline, 1 barrier/step, XOR swizzle: 96.6us.
// R9:  BK=64 w/ arrays in lambda -> scratch spill, 331us (SROA lesson).
// R12: BK=64 scalarized: 91.6us, MfmaUtil 35%. Budget: LDS traffic
//      (64KB rd + 32KB wr per block-step) is ~50% of step time.
// R13: B direct-from-global, SAME-step consumption: 162us, MfmaUtil 19%.
//      Correctness held; latency NOT hidden (only ~300cy cover) and 16-seg
//      scattered B loads all on critical path. Diagnosis: timing, not idea.
// R14 (this): B direct-from-global, ONE STEP AHEAD into a second reg set.
//      Main loop unrolled 2x -> E/O B-reg sets + LDS dbuf index fully
//      static. B(s+1) issued during step s; cover = full step (~2000cy).
//      LDS traffic halves vs R12 (A only: 32KB rd + 16KB wr /block-step).
//      Predict: conv ~60-72us, MfmaUtil 45-55%, LDS 33KB, WRITE ~33MB
//      (spill tripwire), FETCH 36-42MB.

#define BATCH   16
#define CIN     512
#define COUT    512
#define IMG     32
#define PAD_IMG 34

static constexpr float AFF_SCALE = 0.044194173824159216f;  // 1/sqrt(512)
static constexpr float W_SCALE   = 0.014731391274719739f;  // 1/sqrt(512*9)

typedef __bf16 bf16x8 __attribute__((ext_vector_type(8)));
typedef float  f32x4  __attribute__((ext_vector_type(4)));

__device__ inline unsigned short f2bf(float f) {
    union { float f; unsigned int u; } v; v.f = f;
    unsigned int u = v.u;
    unsigned int r = (u + 0x7FFFu + ((u >> 16) & 1u)) >> 16;
    return (unsigned short)r;
}

__device__ inline float waveReduceSum(float v) {
    #pragma unroll
    for (int off = 32; off > 0; off >>= 1) v += __shfl_xor(v, off, 64);
    return v;
}

// ---- kernel 1: fused prep ----
__global__ void prep1(const float* __restrict__ cw,
                      const float* __restrict__ style,
                      const float* __restrict__ aw,
                      const float* __restrict__ ab,
                      unsigned short* __restrict__ w_t,
                      float* __restrict__ wsq,
                      float* __restrict__ s_out) {
    const int tid = threadIdx.x;
    if (blockIdx.x < 1024) {
        __shared__ float wl[2304];
        const float* src = cw + (size_t)blockIdx.x * 2304;
        for (int j = tid; j < 2304; j += 256) wl[j] = src[j];
        __syncthreads();
        const int idx = blockIdx.x * 256 + tid;       // o*512 + i
        const int base = tid * 9;
        float acc = 0.f;
        #pragma unroll
        for (int e = 0; e < 9; ++e) {
            float v = wl[base + e];
            acc += v * v;
            w_t[e * (COUT * CIN) + idx] = f2bf(v);
        }
        wsq[idx] = acc;
    } else {
        const int q = blockIdx.x - 1024;              // 0..2047
        const int b = q >> 7;
        const int i = (q & 127) * 4 + (tid >> 6);
        const int lane = tid & 63;
        float sum = 0.f;
        #pragma unroll
        for (int k = 0; k < 512; k += 64)
            sum += style[b * 512 + k + lane] * aw[i * 512 + k + lane];
        sum = waveReduceSum(sum);
        if (lane == 0)
            s_out[b * 512 + i] = sum * AFF_SCALE + ab[i] + 1.0f;
    }
}

// ---- kernel 2: fused xpad + scale ----
__global__ void prep2(const float* __restrict__ x,
                      const float* __restrict__ s_in,
                      const float* __restrict__ wsq,
                      unsigned short* __restrict__ xpad,
                      float* __restrict__ scl) {
    const int tid = threadIdx.x;
    if (blockIdx.x >= 4352) {
        const int q = blockIdx.x - 4352;              // 0..2047
        const int b = q >> 7;                         // 0..15
        const int o = (q & 127) * 4 + (tid >> 6);     // 0..511
        const int lane = tid & 63;
        float sum = 0.f;
        #pragma unroll
        for (int i = 0; i < 512; i += 64) {
            float sv = s_in[b * 512 + i + lane];
            sum += sv * sv * wsq[o * 512 + i + lane];
        }
        sum = waveReduceSum(sum);
        if (lane == 0)
            scl[b * 512 + o] = W_SCALE * rsqrtf(W_SCALE * W_SCALE * sum + 1e-8f);
        return;
    }
    const int c0   = blockIdx.x & 7;                  // *64 channels
    const int rest = blockIdx.x >> 3;                 // 0..543
    const int hh   = rest % 34;
    const int b    = rest / 34;
    const int c0b  = c0 * 64;
    unsigned short* rowbase = xpad + (((size_t)b * PAD_IMG + hh) * PAD_IMG) * 512;

    if (hh == 0 || hh == PAD_IMG - 1) {
        for (int j = tid; j < 34 * 32; j += 256) {
            int ww = j >> 5, cp = (j & 31) * 2;
            *(unsigned int*)(rowbase + (size_t)ww * 512 + c0b + cp) = 0u;
        }
        return;
    }

    __shared__ float t[64][33];
    const int h = hh - 1;
    {
        const int wx = tid & 31;
        const int cb = (tid >> 5) * 8;
        const float* xb = x + (((size_t)b * 512 + c0b + cb) * IMG + h) * IMG + wx;
        #pragma unroll
        for (int j = 0; j < 8; ++j)
            t[cb + j][wx] = xb[(size_t)j * (IMG * IMG)] * s_in[b * 512 + c0b + cb + j];
    }
    __syncthreads();
    {
        const int p  = tid >> 3;
        const int cc = (tid & 7) * 8;
        unsigned short* dst = rowbase + (size_t)(p + 1) * 512 + c0b + cc;
        uint4 pk;
        pk.x = (unsigned)f2bf(t[cc + 0][p]) | ((unsigned)f2bf(t[cc + 1][p]) << 16);
        pk.y = (unsigned)f2bf(t[cc + 2][p]) | ((unsigned)f2bf(t[cc + 3][p]) << 16);
        pk.z = (unsigned)f2bf(t[cc + 4][p]) | ((unsigned)f2bf(t[cc + 5][p]) << 16);
        pk.w = (unsigned)f2bf(t[cc + 6][p]) | ((unsigned)f2bf(t[cc + 7][p]) << 16);
        *(uint4*)dst = pk;
    }
    if (tid < 64) {
        int ww = (tid >> 5) ? (PAD_IMG - 1) : 0;
        int cp = (tid & 31) * 2;
        *(unsigned int*)(rowbase + (size_t)ww * 512 + c0b + cp) = 0u;
    }
}

// ---- kernel 3: implicit-GEMM conv, 128x128 tile, BK=64, bf16 MFMA ----
// A: LDS-staged (reg prefetch, dbuf, XOR swizzle). B: direct from global,
// prefetched ONE STEP AHEAD into alternating E/O reg sets (2x-unrolled
// loop -> all indices static). One barrier per step, 32 MFMA/wave/step.
// grid 512 (XCD-swizzled), block 256 (4 waves), 2 blocks/CU.

// A loader: step -> 4 named uint4 regs (128x64 slab)
#define LOADA(stp) do {                                                       \
    const int eA_  = (stp) >> 3;                                              \
    const int kcA_ = ((stp) & 7) << 6;                                        \
    const unsigned short* Ab_ = wt + (size_t)eA_ * (COUT * CIN)               \
                                   + (size_t)m0 * 512 + kcA_;                 \
    ra0 = *(const uint4*)(Ab_ + aOff0);                                       \
    ra1 = *(const uint4*)(Ab_ + aOff1);                                       \
    ra2 = *(const uint4*)(Ab_ + aOff2);                                       \
    ra3 = *(const uint4*)(Ab_ + aOff3);                                       \
} while (0)

// B loader into reg set q0..q7 (frags consumed directly by MFMA next step).
// q0..3 = half-cluster k 0..31 (ni 0..3); q4..7 = k 32..63.
#define LOADB(stp, q0, q1, q2, q3, q4, q5, q6, q7) do {                       \
    const int eB_  = (stp) >> 3;                                              \
    const int kcB_ = ((stp) & 7) << 6;                                        \
    const int khB_ = (eB_ * 11) >> 5;                                         \
    const int kwB_ = eB_ - khB_ * 3;                                          \
    const unsigned short* Bb_ = xpad + bImgBase                               \
        + (size_t)((h0 + khB_) * PAD_IMG + kwB_) * 512 + kcB_;                \
    q0 = *(const uint4*)(Bb_ + pOff0);                                        \
    q1 = *(const uint4*)(Bb_ + pOff1);                                        \
    q2 = *(const uint4*)(Bb_ + pOff2);                                        \
    q3 = *(const uint4*)(Bb_ + pOff3);                                        \
    q4 = *(const uint4*)(Bb_ + pOff0 + 32);                                   \
    q5 = *(const uint4*)(Bb_ + pOff1 + 32);                                   \
    q6 = *(const uint4*)(Bb_ + pOff2 + 32);                                   \
    q7 = *(const uint4*)(Bb_ + pOff3 + 32);                                   \
} while (0)

// MFMA compute for one step: A frags from Alds[bufidx], B from reg set.
#define COMPUTE(bufidx, q0, q1, q2, q3, q4, q5, q6, q7) do {                  \
    bf16x8 af0_, af1_, af2_, af3_;                                            \
    af0_ = *(const bf16x8*)(&Alds[bufidx][arow + 0 * (16 * 64) + swz0]);      \
    af1_ = *(const bf16x8*)(&Alds[bufidx][arow + 1 * (16 * 64) + swz0]);      \
    af2_ = *(const bf16x8*)(&Alds[bufidx][arow + 2 * (16 * 64) + swz0]);      \
    af3_ = *(const bf16x8*)(&Alds[bufidx][arow + 3 * (16 * 64) + swz0]);      \
    const bf16x8 b0_ = __builtin_bit_cast(bf16x8, q0);                        \
    const bf16x8 b1_ = __builtin_bit_cast(bf16x8, q1);                        \
    const bf16x8 b2_ = __builtin_bit_cast(bf16x8, q2);                        \
    const bf16x8 b3_ = __builtin_bit_cast(bf16x8, q3);                        \
    __builtin_amdgcn_s_setprio(1);                                            \
    acc[0][0] = __builtin_amdgcn_mfma_f32_16x16x32_bf16(af0_, b0_, acc[0][0], 0, 0, 0); \
    acc[0][1] = __builtin_amdgcn_mfma_f32_16x16x32_bf16(af0_, b1_, acc[0][1], 0, 0, 0); \
    acc[0][2] = __builtin_amdgcn_mfma_f32_16x16x32_bf16(af0_, b2_, acc[0][2], 0, 0, 0); \
    acc[0][3] = __builtin_amdgcn_mfma_f32_16x16x32_bf16(af0_, b3_, acc[0][3], 0, 0, 0); \
    acc[1][0] = __builtin_amdgcn_mfma_f32_16x16x32_bf16(af1_, b0_, acc[1][0], 0, 0, 0); \
    acc[1][1] = __builtin_amdgcn_mfma_f32_16x16x32_bf16(af1_, b1_, acc[1][1], 0, 0, 0); \
    acc[1][2] = __builtin_amdgcn_mfma_f32_16x16x32_bf16(af1_, b2_, acc[1][2], 0, 0, 0); \
    acc[1][3] = __builtin_amdgcn_mfma_f32_16x16x32_bf16(af1_, b3_, acc[1][3], 0, 0, 0); \
    acc[2][0] = __builtin_amdgcn_mfma_f32_16x16x32_bf16(af2_, b0_, acc[2][0], 0, 0, 0); \
    acc[2][1] = __builtin_amdgcn_mfma_f32_16x16x32_bf16(af2_, b1_, acc[2][1], 0, 0, 0); \
    acc[2][2] = __builtin_amdgcn_mfma_f32_16x16x32_bf16(af2_, b2_, acc[2][2], 0, 0, 0); \
    acc[2][3] = __builtin_amdgcn_mfma_f32_16x16x32_bf16(af2_, b3_, acc[2][3], 0, 0, 0); \
    acc[3][0] = __builtin_amdgcn_mfma_f32_16x16x32_bf16(af3_, b0_, acc[3][0], 0, 0, 0); \
    acc[3][1] = __builtin_amdgcn_mfma_f32_16x16x32_bf16(af3_, b1_, acc[3][1], 0, 0, 0); \
    acc[3][2] = __builtin_amdgcn_mfma_f32_16x16x32_bf16(af3_, b2_, acc[3][2], 0, 0, 0); \
    acc[3][3] = __builtin_amdgcn_mfma_f32_16x16x32_bf16(af3_, b3_, acc[3][3], 0, 0, 0); \
    __builtin_amdgcn_s_setprio(0);                                            \
    af0_ = *(const bf16x8*)(&Alds[bufidx][arow + 0 * (16 * 64) + swz1]);      \
    af1_ = *(const bf16x8*)(&Alds[bufidx][arow + 1 * (16 * 64) + swz1]);      \
    af2_ = *(const bf16x8*)(&Alds[bufidx][arow + 2 * (16 * 64) + swz1]);      \
    af3_ = *(const bf16x8*)(&Alds[bufidx][arow + 3 * (16 * 64) + swz1]);      \
    const bf16x8 b4_ = __builtin_bit_cast(bf16x8, q4);                        \
    const bf16x8 b5_ = __builtin_bit_cast(bf16x8, q5);                        \
    const bf16x8 b6_ = __builtin_bit_cast(bf16x8, q6);                        \
    const bf16x8 b7_ = __builtin_bit_cast(bf16x8, q7);                        \
    __builtin_amdgcn_s_setprio(1);                                            \
    acc[0][0] = __builtin_amdgcn_mfma_f32_16x16x32_bf16(af0_, b4_, acc[0][0], 0, 0, 0); \
    acc[0][1] = __builtin_amdgcn_mfma_f32_16x16x32_bf16(af0_, b5_, acc[0][1], 0, 0, 0); \
    acc[0][2] = __builtin_amdgcn_mfma_f32_16x16x32_bf16(af0_, b6_, acc[0][2], 0, 0, 0); \
    acc[0][3] = __builtin_amdgcn_mfma_f32_16x16x32_bf16(af0_, b7_, acc[0][3], 0, 0, 0); \
    acc[1][0] = __builtin_amdgcn_mfma_f32_16x16x32_bf16(af1_, b4_, acc[1][0], 0, 0, 0); \
    acc[1][1] = __builtin_amdgcn_mfma_f32_16x16x32_bf16(af1_, b5_, acc[1][1], 0, 0, 0); \
    acc[1][2] = __builtin_amdgcn_mfma_f32_16x16x32_bf16(af1_, b6_, acc[1][2], 0, 0, 0); \
    acc[1][3] = __builtin_amdgcn_mfma_f32_16x16x32_bf16(af1_, b7_, acc[1][3], 0, 0, 0); \
    acc[2][0] = __builtin_amdgcn_mfma_f32_16x16x32_bf16(af2_, b4_, acc[2][0], 0, 0, 0); \
    acc[2][1] = __builtin_amdgcn_mfma_f32_16x16x32_bf16(af2_, b5_, acc[2][1], 0, 0, 0); \
    acc[2][2] = __builtin_amdgcn_mfma_f32_16x16x32_bf16(af2_, b6_, acc[2][2], 0, 0, 0); \
    acc[2][3] = __builtin_amdgcn_mfma_f32_16x16x32_bf16(af2_, b7_, acc[2][3], 0, 0, 0); \
    acc[3][0] = __builtin_amdgcn_mfma_f32_16x16x32_bf16(af3_, b4_, acc[3][0], 0, 0, 0); \
    acc[3][1] = __builtin_amdgcn_mfma_f32_16x16x32_bf16(af3_, b5_, acc[3][1], 0, 0, 0); \
    acc[3][2] = __builtin_amdgcn_mfma_f32_16x16x32_bf16(af3_, b6_, acc[3][2], 0, 0, 0); \
    acc[3][3] = __builtin_amdgcn_mfma_f32_16x16x32_bf16(af3_, b7_, acc[3][3], 0, 0, 0); \
    __builtin_amdgcn_s_setprio(0);                                            \
} while (0)

#define COMMITA(bufidx) do {                                                  \
    *(uint4*)(&Alds[bufidx][lOff0]) = ra0;                                    \
    *(uint4*)(&Alds[bufidx][lOff1]) = ra1;                                    \
    *(uint4*)(&Alds[bufidx][lOff2]) = ra2;                                    \
    *(uint4*)(&Alds[bufidx][lOff3]) = ra3;                                    \
} while (0)

__global__ __launch_bounds__(256, 2) void conv_mfma(
    const unsigned short* __restrict__ wt,    // [9][512][512] bf16
    const unsigned short* __restrict__ xpad,  // [16][34][34][512] bf16
    const float* __restrict__ scl,            // [16][512]
    float* __restrict__ out)                  // [16][512][32][32]
{
    __shared__ __align__(16) unsigned short Alds[2][128 * 64];  // 2 x 16 KB
    __shared__ float sclds[128];

    const int tid = threadIdx.x;
    // XCD swizzle: id&7 -> XCD. Each XCD: 16 (h,b)-pairs x 4 m-blocks.
    const int id    = blockIdx.x;
    const int xcd   = id & 7;
    const int local = id >> 3;                   // 0..63
    const int gp    = xcd * 16 + (local >> 2);   // 0..127  (h,b) pair
    const int m0  = (local & 3) * 128;
    const int h0  = (gp & 7) * 4;
    const int b   = gp >> 3;

    if (tid < 128) sclds[tid] = scl[b * 512 + m0 + tid];

    const int wid  = tid >> 6;
    const int lane = tid & 63;
    const int wm = wid & 1, wn = wid >> 1;

    const f32x4 vzero = {0.f, 0.f, 0.f, 0.f};
    f32x4 acc[4][4];
    #pragma unroll
    for (int i = 0; i < 4; ++i)
        #pragma unroll
        for (int j = 0; j < 4; ++j) acc[i][j] = vzero;

    // A staging: thread f = r*256+tid owns (row=f>>3, chunk c=f&7) of the
    // 128x64 A tile. LDS slot XOR-swizzled: p = c ^ (row&7). All offsets
    // NAMED SCALARS (R9 lesson: arrays in the loader -> scratch spill).
    int aOff0, aOff1, aOff2, aOff3;
    int lOff0, lOff1, lOff2, lOff3;
    {
        int f, row, c, p;
        f = tid;             row = f >> 3; c = f & 7; p = c ^ (row & 7);
        aOff0 = row * 512 + c * 8;  lOff0 = row * 64 + p * 8;
        f = 256 + tid;       row = f >> 3; c = f & 7; p = c ^ (row & 7);
        aOff1 = row * 512 + c * 8;  lOff1 = row * 64 + p * 8;
        f = 512 + tid;       row = f >> 3; c = f & 7; p = c ^ (row & 7);
        aOff2 = row * 512 + c * 8;  lOff2 = row * 64 + p * 8;
        f = 768 + tid;       row = f >> 3; c = f & 7; p = c ^ (row & 7);
        aOff3 = row * 512 + c * 8;  lOff3 = row * 64 + p * 8;
    }

    const size_t bImgBase = (size_t)b * PAD_IMG * PAD_IMG * 512;

    // fragment geometry
    const int rl   = lane & 15;
    const int kch  = lane >> 4;                  // 0..3 (8-ch chunk within k32)
    // A LDS read swizzle: chunk (ks*4+kch) at position ^(row&7); wbase%16==0.
    const int sw   = rl & 7;
    const int swz0 = (kch ^ sw) * 8;             // k 0..31
    const int swz1 = ((kch + 4) ^ sw) * 8;       // k 32..63
    const int arow = (wm * 64 + rl) * 64;
    // B per-lane pixel offsets (shorts), constant per lane: frag ni reads
    // pixel prow = wn*64 + ni*16 + rl; img row = prow>>5, col = prow&31;
    // + channel chunk kch*8. (Validated in R13.)
    int pOff0, pOff1, pOff2, pOff3;
    {
        int pr;
        pr = wn * 64 + 0 * 16 + rl;
        pOff0 = ((pr >> 5) * PAD_IMG + (pr & 31)) * 512 + kch * 8;
        pr = wn * 64 + 1 * 16 + rl;
        pOff1 = ((pr >> 5) * PAD_IMG + (pr & 31)) * 512 + kch * 8;
        pr = wn * 64 + 2 * 16 + rl;
        pOff2 = ((pr >> 5) * PAD_IMG + (pr & 31)) * 512 + kch * 8;
        pr = wn * 64 + 3 * 16 + rl;
        pOff3 = ((pr >> 5) * PAD_IMG + (pr & 31)) * 512 + kch * 8;
    }

    // prefetch state: named uint4 scalars (SROA-safe)
    uint4 ra0, ra1, ra2, ra3;                          // A slab (next step)
    uint4 eb0, eb1, eb2, eb3, eb4, eb5, eb6, eb7;      // B frags, even steps
    uint4 ob0, ob1, ob2, ob3, ob4, ob5, ob6, ob7;      // B frags, odd steps

    LOADA(0);
    LOADB(0, eb0, eb1, eb2, eb3, eb4, eb5, eb6, eb7);

    // 72 steps as 36 double-iterations; all buffer/reg-set indices static.
    for (int t = 0; t < 36; ++t) {
        const int s = 2 * t;
        // ---- even phase: compute step s (B in E regs, A -> Alds[0]) ----
        COMMITA(0);                               // waits only on ra (oldest)
        LOADA(s + 1);
        LOADB(s + 1, ob0, ob1, ob2, ob3, ob4, ob5, ob6, ob7);
        __syncthreads();
        COMPUTE(0, eb0, eb1, eb2, eb3, eb4, eb5, eb6, eb7);
        // ---- odd phase: compute step s+1 (B in O regs, A -> Alds[1]) ----
        COMMITA(1);
        {
            const int nxt = (s + 2 < 72) ? s + 2 : 71;
            LOADA(nxt);
            LOADB(nxt, eb0, eb1, eb2, eb3, eb4, eb5, eb6, eb7);
        }
        __syncthreads();
        COMPUTE(1, ob0, ob1, ob2, ob3, ob4, ob5, ob6, ob7);
        // barrier-safety: write to Alds[p] at phase t+1 is separated from
        // its last readers (phase t's COMPUTE) by the opposite phase's
        // barrier; readers' lgkm waits complete before they reach it.
    }

    // epilogue: C[m][n] layout col=lane&15, row=(lane>>4)*4+reg  [m89-verified]
    const int colp = lane & 15;
    const int rowq = (lane >> 4) * 4;
    const int p0 = h0 * 32;
    #pragma unroll
    for (int mi = 0; mi < 4; ++mi) {
        #pragma unroll
        for (int ni = 0; ni < 4; ++ni) {
            const int p = p0 + wn * 64 + ni * 16 + colp;
            #pragma unroll
            for (int r2 = 0; r2 < 4; ++r2) {
                const int ol = wm * 64 + mi * 16 + rowq + r2;
                out[(((size_t)b * 512 + m0 + ol) << 10) + p] =
                    acc[mi][ni][r2] * sclds[ol];
            }
        }
    }
}

extern "C" void kernel_launch(void* const* d_in, const int* in_sizes, int n_in,
                              void* d_out, int out_size, void* d_ws, size_t ws_size,
                              hipStream_t stream) {
    const float* x     = (const float*)d_in[0];  // [16,512,32,32]
    const float* style = (const float*)d_in[1];  // [16,512]
    const float* aw    = (const float*)d_in[2];  // [512,512]
    const float* ab    = (const float*)d_in[3];  // [512]
    const float* cw    = (const float*)d_in[4];  // [512,512,3,3]
    float* out = (float*)d_out;

    char* ws = (char*)d_ws;
    float* s_buf          = (float*)(ws);                      //  32 KB
    float* scl            = (float*)(ws + 32768);              //  32 KB
    float* wsq            = (float*)(ws + 65536);              //   1 MB
    unsigned short* w_t   = (unsigned short*)(ws + 1114112);   // 4.5 MB bf16
    unsigned short* x_pad = (unsigned short*)(ws + 5832704);   // 18.9 MB bf16
    // total ws need: 24,772,608 B

    prep1<<<dim3(3072), 256, 0, stream>>>(cw, style, aw, ab, w_t, wsq, s_buf);
    prep2<<<dim3(6400), 256, 0, stream>>>(x, s_buf, wsq, x_pad, scl);
    conv_mfma<<<dim3(512), 256, 0, stream>>>(w_t, x_pad, scl, out);
}

// Round 7
// 178.188 us; speedup vs baseline: 1.3749x; 1.3749x over previous
//
#include <hip/hip_runtime.h>

// ModulatedConv2d: B=16, IN=512, OUT=512, STYLE=512, K=3, H=W=32
// out[b,o] = scale[b,o] * conv2d(x[b,i]*s[b,i], W[o,i])   (shared weights!)
// Conv = one implicit GEMM: M=512 out-ch, N=16384 (b,px), K=9x512.
// x staged as zero-padded NHWC bf16 -> no boundary masking.
//
// R8:  reg-staged A+B LDS pipeline, 1 __syncthreads/step, XOR swz: 96.6us.
// R9:  BK=64 w/ arrays in loader -> scratch spill, 331us (SROA lesson).
// R12: BK=64 scalarized: 91.6us, MfmaUtil 35%. Best measured.
// R13: B direct-from-global same-step: 162us, MfmaUtil 19% (scattered).
// R14: B direct one-step-ahead: 160us, SAME as R13 -> scattered B loads are
//      THROUGHPUT-bound (16x 64B segments/wave-load), not latency. B-direct
//      abandoned; B back to LDS staging.
// R15 (this): R12 + RAW BARRIER. Theory: __syncthreads lowers to fence+
//      s_barrier+fence and emits s_waitcnt vmcnt(0) -> drains the A/B
//      VGPR prefetch EVERY step, exposing L2 latency once per step
//      (~1100cy residual in the step budget). Replace with
//      {s_waitcnt lgkmcnt(0); s_barrier; sched_barrier(0)} -- ds_write->
//      barrier->ds_read only needs lgkm; prefetch loads stay in flight.
//      + T5 setprio(1) around MFMA half-clusters (2 indep blocks/CU).
//      Predict: conv ~60-70us MfmaUtil 45-55% if drain was real;
//      neutral ~90us if not. FETCH ~29MB, WRITE ~33MB, conflicts 0.

#define BATCH   16
#define CIN     512
#define COUT    512
#define IMG     32
#define PAD_IMG 34

static constexpr float AFF_SCALE = 0.044194173824159216f;  // 1/sqrt(512)
static constexpr float W_SCALE   = 0.014731391274719739f;  // 1/sqrt(512*9)

typedef __bf16 bf16x8 __attribute__((ext_vector_type(8)));
typedef float  f32x4  __attribute__((ext_vector_type(4)));

__device__ inline unsigned short f2bf(float f) {
    union { float f; unsigned int u; } v; v.f = f;
    unsigned int u = v.u;
    unsigned int r = (u + 0x7FFFu + ((u >> 16) & 1u)) >> 16;
    return (unsigned short)r;
}

__device__ inline float waveReduceSum(float v) {
    #pragma unroll
    for (int off = 32; off > 0; off >>= 1) v += __shfl_xor(v, off, 64);
    return v;
}

// ---- kernel 1: fused prep ----
__global__ void prep1(const float* __restrict__ cw,
                      const float* __restrict__ style,
                      const float* __restrict__ aw,
                      const float* __restrict__ ab,
                      unsigned short* __restrict__ w_t,
                      float* __restrict__ wsq,
                      float* __restrict__ s_out) {
    const int tid = threadIdx.x;
    if (blockIdx.x < 1024) {
        __shared__ float wl[2304];
        const float* src = cw + (size_t)blockIdx.x * 2304;
        for (int j = tid; j < 2304; j += 256) wl[j] = src[j];
        __syncthreads();
        const int idx = blockIdx.x * 256 + tid;       // o*512 + i
        const int base = tid * 9;
        float acc = 0.f;
        #pragma unroll
        for (int e = 0; e < 9; ++e) {
            float v = wl[base + e];
            acc += v * v;
            w_t[e * (COUT * CIN) + idx] = f2bf(v);
        }
        wsq[idx] = acc;
    } else {
        const int q = blockIdx.x - 1024;              // 0..2047
        const int b = q >> 7;
        const int i = (q & 127) * 4 + (tid >> 6);
        const int lane = tid & 63;
        float sum = 0.f;
        #pragma unroll
        for (int k = 0; k < 512; k += 64)
            sum += style[b * 512 + k + lane] * aw[i * 512 + k + lane];
        sum = waveReduceSum(sum);
        if (lane == 0)
            s_out[b * 512 + i] = sum * AFF_SCALE + ab[i] + 1.0f;
    }
}

// ---- kernel 2: fused xpad + scale ----
__global__ void prep2(const float* __restrict__ x,
                      const float* __restrict__ s_in,
                      const float* __restrict__ wsq,
                      unsigned short* __restrict__ xpad,
                      float* __restrict__ scl) {
    const int tid = threadIdx.x;
    if (blockIdx.x >= 4352) {
        const int q = blockIdx.x - 4352;              // 0..2047
        const int b = q >> 7;                         // 0..15
        const int o = (q & 127) * 4 + (tid >> 6);     // 0..511
        const int lane = tid & 63;
        float sum = 0.f;
        #pragma unroll
        for (int i = 0; i < 512; i += 64) {
            float sv = s_in[b * 512 + i + lane];
            sum += sv * sv * wsq[o * 512 + i + lane];
        }
        sum = waveReduceSum(sum);
        if (lane == 0)
            scl[b * 512 + o] = W_SCALE * rsqrtf(W_SCALE * W_SCALE * sum + 1e-8f);
        return;
    }
    const int c0   = blockIdx.x & 7;                  // *64 channels
    const int rest = blockIdx.x >> 3;                 // 0..543
    const int hh   = rest % 34;
    const int b    = rest / 34;
    const int c0b  = c0 * 64;
    unsigned short* rowbase = xpad + (((size_t)b * PAD_IMG + hh) * PAD_IMG) * 512;

    if (hh == 0 || hh == PAD_IMG - 1) {
        for (int j = tid; j < 34 * 32; j += 256) {
            int ww = j >> 5, cp = (j & 31) * 2;
            *(unsigned int*)(rowbase + (size_t)ww * 512 + c0b + cp) = 0u;
        }
        return;
    }

    __shared__ float t[64][33];
    const int h = hh - 1;
    {
        const int wx = tid & 31;
        const int cb = (tid >> 5) * 8;
        const float* xb = x + (((size_t)b * 512 + c0b + cb) * IMG + h) * IMG + wx;
        #pragma unroll
        for (int j = 0; j < 8; ++j)
            t[cb + j][wx] = xb[(size_t)j * (IMG * IMG)] * s_in[b * 512 + c0b + cb + j];
    }
    __syncthreads();
    {
        const int p  = tid >> 3;
        const int cc = (tid & 7) * 8;
        unsigned short* dst = rowbase + (size_t)(p + 1) * 512 + c0b + cc;
        uint4 pk;
        pk.x = (unsigned)f2bf(t[cc + 0][p]) | ((unsigned)f2bf(t[cc + 1][p]) << 16);
        pk.y = (unsigned)f2bf(t[cc + 2][p]) | ((unsigned)f2bf(t[cc + 3][p]) << 16);
        pk.z = (unsigned)f2bf(t[cc + 4][p]) | ((unsigned)f2bf(t[cc + 5][p]) << 16);
        pk.w = (unsigned)f2bf(t[cc + 6][p]) | ((unsigned)f2bf(t[cc + 7][p]) << 16);
        *(uint4*)dst = pk;
    }
    if (tid < 64) {
        int ww = (tid >> 5) ? (PAD_IMG - 1) : 0;
        int cp = (tid & 31) * 2;
        *(unsigned int*)(rowbase + (size_t)ww * 512 + c0b + cp) = 0u;
    }
}

// ---- kernel 3: implicit-GEMM conv, 128x128 tile, BK=64, bf16 MFMA ----
// Register-staged pipeline: buffer_load->VGPR prefetch (named scalars),
// ds_write dbuf LDS, one RAW barrier per K-step (lgkm-only drain: global
// prefetch loads stay in flight across it). 32 MFMA/wave/step.
// grid 512 (XCD-swizzled), block 256 (4 waves), 2 blocks/CU (LDS 64KB).

// Raw barrier: ds-ordering only. __syncthreads would emit vmcnt(0) and
// drain the VGPR prefetch every step (the R15 theory). lgkmcnt(0) is
// sufficient: cross-wave dep is ds_write -> barrier -> ds_read only.
// sched_barrier(0) pins code motion across the asm (rule #18).
#define SYNC() do {                                                           \
    asm volatile("s_waitcnt lgkmcnt(0)" ::: "memory");                        \
    __builtin_amdgcn_s_barrier();                                             \
    __builtin_amdgcn_sched_barrier(0);                                        \
} while (0)

// loader: step -> 8 named uint4 regs (A/B 128x64 slabs)
#define LOADSTEP(stp) do {                                                    \
    const int e_  = (stp) >> 3;                                               \
    const int kc_ = ((stp) & 7) << 6;                                         \
    const int kh_ = (e_ * 11) >> 5;                                           \
    const int kw_ = e_ - kh_ * 3;                                             \
    const unsigned short* Ab_ = wt + (size_t)e_ * (COUT * CIN)                \
                                   + (size_t)m0 * 512 + kc_;                  \
    const unsigned short* Bb_ = xpad + bImgBase                               \
                              + (size_t)((h0 + kh_) * PAD_IMG + kw_) * 512    \
                              + kc_;                                          \
    ra0 = *(const uint4*)(Ab_ + aOff0);                                       \
    ra1 = *(const uint4*)(Ab_ + aOff1);                                       \
    ra2 = *(const uint4*)(Ab_ + aOff2);                                       \
    ra3 = *(const uint4*)(Ab_ + aOff3);                                       \
    rb0 = *(const uint4*)(Bb_ + bOff0);                                       \
    rb1 = *(const uint4*)(Bb_ + bOff1);                                       \
    rb2 = *(const uint4*)(Bb_ + bOff2);                                       \
    rb3 = *(const uint4*)(Bb_ + bOff3);                                       \
} while (0)

__global__ __launch_bounds__(256, 2) void conv_mfma(
    const unsigned short* __restrict__ wt,    // [9][512][512] bf16
    const unsigned short* __restrict__ xpad,  // [16][34][34][512] bf16
    const float* __restrict__ scl,            // [16][512]
    float* __restrict__ out)                  // [16][512][32][32]
{
    __shared__ __align__(16) unsigned short Alds[2][128 * 64];  // 2 x 16 KB
    __shared__ __align__(16) unsigned short Blds[2][128 * 64];  // 2 x 16 KB
    __shared__ float sclds[128];

    const int tid = threadIdx.x;
    // XCD swizzle: id&7 -> XCD. Each XCD: 16 (h,b)-pairs x 4 m-blocks.
    const int id    = blockIdx.x;
    const int xcd   = id & 7;
    const int local = id >> 3;                   // 0..63
    const int gp    = xcd * 16 + (local >> 2);   // 0..127  (h,b) pair
    const int m0  = (local & 3) * 128;
    const int h0  = (gp & 7) * 4;
    const int b   = gp >> 3;

    if (tid < 128) sclds[tid] = scl[b * 512 + m0 + tid];

    const int wid  = tid >> 6;
    const int lane = tid & 63;
    const int wm = wid & 1, wn = wid >> 1;

    const f32x4 vzero = {0.f, 0.f, 0.f, 0.f};
    f32x4 acc[4][4];
    #pragma unroll
    for (int i = 0; i < 4; ++i)
        #pragma unroll
        for (int j = 0; j < 4; ++j) acc[i][j] = vzero;

    // staging: thread f = r*256+tid owns (row=f>>3, chunk c=f&7) of the
    // 128x64 tile (chunk = 8 shorts = 16B). LDS slot XOR-swizzled:
    // p = c ^ (row&7). All offsets NAMED SCALARS (R9 lesson: arrays in
    // the loader fail SROA -> scratch spill).
    int aOff0, aOff1, aOff2, aOff3;
    int bOff0, bOff1, bOff2, bOff3;
    int lOff0, lOff1, lOff2, lOff3;
    {
        int f, row, c, p;
        f = tid;             row = f >> 3; c = f & 7; p = c ^ (row & 7);
        aOff0 = row * 512 + c * 8;
        bOff0 = ((row >> 5) * PAD_IMG + (row & 31)) * 512 + c * 8;
        lOff0 = row * 64 + p * 8;
        f = 256 + tid;       row = f >> 3; c = f & 7; p = c ^ (row & 7);
        aOff1 = row * 512 + c * 8;
        bOff1 = ((row >> 5) * PAD_IMG + (row & 31)) * 512 + c * 8;
        lOff1 = row * 64 + p * 8;
        f = 512 + tid;       row = f >> 3; c = f & 7; p = c ^ (row & 7);
        aOff2 = row * 512 + c * 8;
        bOff2 = ((row >> 5) * PAD_IMG + (row & 31)) * 512 + c * 8;
        lOff2 = row * 64 + p * 8;
        f = 768 + tid;       row = f >> 3; c = f & 7; p = c ^ (row & 7);
        aOff3 = row * 512 + c * 8;
        bOff3 = ((row >> 5) * PAD_IMG + (row & 31)) * 512 + c * 8;
        lOff3 = row * 64 + p * 8;
    }

    const size_t bImgBase = (size_t)b * PAD_IMG * PAD_IMG * 512;

    // prefetch state: 8 named uint4 scalars (SROA-safe)
    uint4 ra0, ra1, ra2, ra3, rb0, rb1, rb2, rb3;

    LOADSTEP(0);

    // fragment read addresses (shorts): row R = wbase+rl; k-slice ks reads
    // chunk (ks*4+kch) at swizzled position (ks*4+kch)^(R&7); wbase%16==0
    // so R&7 = rl&7.
    const int rl   = lane & 15;
    const int kch  = lane >> 4;                  // 0..3
    const int sw   = rl & 7;
    const int swz0 = (kch ^ sw) * 8;             // k 0..31
    const int swz1 = ((kch + 4) ^ sw) * 8;       // k 32..63
    const int arow = (wm * 64 + rl) * 64;
    const int brow = (wn * 64 + rl) * 64;

    for (int step = 0; step < 72; ++step) {
        const int buf = step & 1;
        // commit prefetched regs to LDS (vmcnt wait here is for loads issued
        // one full iteration ago -- hidden behind compute(step-1))
        *(uint4*)(&Alds[buf][lOff0]) = ra0;
        *(uint4*)(&Alds[buf][lOff1]) = ra1;
        *(uint4*)(&Alds[buf][lOff2]) = ra2;
        *(uint4*)(&Alds[buf][lOff3]) = ra3;
        *(uint4*)(&Blds[buf][lOff0]) = rb0;
        *(uint4*)(&Blds[buf][lOff1]) = rb1;
        *(uint4*)(&Blds[buf][lOff2]) = rb2;
        *(uint4*)(&Blds[buf][lOff3]) = rb3;
        // issue next step's loads; they remain in flight across the barrier
        const int nxt = step + 1 < 72 ? step + 1 : 71;
        LOADSTEP(nxt);
        SYNC();

        // half-cluster 1: k 0..31
        {
            bf16x8 af[4], bfr[4];
            #pragma unroll
            for (int mi = 0; mi < 4; ++mi)
                af[mi] = *(const bf16x8*)(&Alds[buf][arow + mi * (16 * 64) + swz0]);
            #pragma unroll
            for (int ni = 0; ni < 4; ++ni)
                bfr[ni] = *(const bf16x8*)(&Blds[buf][brow + ni * (16 * 64) + swz0]);
            __builtin_amdgcn_s_setprio(1);
            #pragma unroll
            for (int mi = 0; mi < 4; ++mi)
                #pragma unroll
                for (int ni = 0; ni < 4; ++ni)
                    acc[mi][ni] = __builtin_amdgcn_mfma_f32_16x16x32_bf16(
                        af[mi], bfr[ni], acc[mi][ni], 0, 0, 0);
            __builtin_amdgcn_s_setprio(0);
        }
        // half-cluster 2: k 32..63
        {
            bf16x8 af[4], bfr[4];
            #pragma unroll
            for (int mi = 0; mi < 4; ++mi)
                af[mi] = *(const bf16x8*)(&Alds[buf][arow + mi * (16 * 64) + swz1]);
            #pragma unroll
            for (int ni = 0; ni < 4; ++ni)
                bfr[ni] = *(const bf16x8*)(&Blds[buf][brow + ni * (16 * 64) + swz1]);
            __builtin_amdgcn_s_setprio(1);
            #pragma unroll
            for (int mi = 0; mi < 4; ++mi)
                #pragma unroll
                for (int ni = 0; ni < 4; ++ni)
                    acc[mi][ni] = __builtin_amdgcn_mfma_f32_16x16x32_bf16(
                        af[mi], bfr[ni], acc[mi][ni], 0, 0, 0);
            __builtin_amdgcn_s_setprio(0);
        }
        // barrier-safety (raw SYNC): every wave drains its lgkm (ds_reads
        // AND ds_writes) before entering barrier(step); the step+1 writes
        // to buf^1 occur after barrier(step), so step-1's readers of buf^1
        // are provably complete. Global loads legitimately cross.
    }

    // epilogue: C[m][n] layout col=lane&15, row=(lane>>4)*4+reg  [m89-verified]
    const int colp = lane & 15;
    const int rowq = (lane >> 4) * 4;
    const int p0 = h0 * 32;
    #pragma unroll
    for (int mi = 0; mi < 4; ++mi) {
        #pragma unroll
        for (int ni = 0; ni < 4; ++ni) {
            const int p = p0 + wn * 64 + ni * 16 + colp;
            #pragma unroll
            for (int r2 = 0; r2 < 4; ++r2) {
                const int ol = wm * 64 + mi * 16 + rowq + r2;
                out[(((size_t)b * 512 + m0 + ol) << 10) + p] =
                    acc[mi][ni][r2] * sclds[ol];
            }
        }
    }
}

extern "C" void kernel_launch(void* const* d_in, const int* in_sizes, int n_in,
                              void* d_out, int out_size, void* d_ws, size_t ws_size,
                              hipStream_t stream) {
    const float* x     = (const float*)d_in[0];  // [16,512,32,32]
    const float* style = (const float*)d_in[1];  // [16,512]
    const float* aw    = (const float*)d_in[2];  // [512,512]
    const float* ab    = (const float*)d_in[3];  // [512]
    const float* cw    = (const float*)d_in[4];  // [512,512,3,3]
    float* out = (float*)d_out;

    char* ws = (char*)d_ws;
    float* s_buf          = (float*)(ws);                      //  32 KB
    float* scl            = (float*)(ws + 32768);              //  32 KB
    float* wsq            = (float*)(ws + 65536);              //   1 MB
    unsigned short* w_t   = (unsigned short*)(ws + 1114112);   // 4.5 MB bf16
    unsigned short* x_pad = (unsigned short*)(ws + 5832704);   // 18.9 MB bf16
    // total ws need: 24,772,608 B

    prep1<<<dim3(3072), 256, 0, stream>>>(cw, style, aw, ab, w_t, wsq, s_buf);
    prep2<<<dim3(6400), 256, 0, stream>>>(x, s_buf, wsq, x_pad, scl);
    conv_mfma<<<dim3(512), 256, 0, stream>>>(w_t, x_pad, scl, out);
}